// Round 8
// baseline (201.138 us; speedup 1.0000x reference)
//
#include <hip/hip_runtime.h>
#include <hip/hip_fp16.h>

#define NN   100000
#define EE   1250000
#define DIN  128
#define HID  64
#define DOUT 40

#define BN   512                  // nodes per bucket
#define NB   196                  // ceil(NN/BN)
#define CH   4096                 // edges per scatter block (16/thread)
#define SEG  8192                 // ebuf stride (raw edges; mean 6377, 22 sigma)
#define SEG2 10240                // esrc stride (8-padded lists; mean ~8170, big margin)
#define S_BLKS 306                // ceil(EE/CH)
#define G_BLKS 1563               // ceil(NN/64)

typedef _Float16 v8h __attribute__((ext_vector_type(8)));
typedef float    v4f __attribute__((ext_vector_type(4)));

// unpack a float4-of-8-halves and accumulate into 2 float4s
__device__ __forceinline__ void acc8(const float4& v, float4& lo, float4& hi) {
    const __half2* hp = (const __half2*)&v;
    float2 f0 = __half22float2(hp[0]), f1 = __half22float2(hp[1]);
    float2 f2 = __half22float2(hp[2]), f3 = __half22float2(hp[3]);
    lo.x += f0.x; lo.y += f0.y; lo.z += f1.x; lo.w += f1.y;
    hi.x += f2.x; hi.y += f2.y; hi.z += f3.x; hi.w += f3.y;
}

// scale by d, convert to 8 halves, store 16B
__device__ __forceinline__ void sthalf8(__half* p, const float4& lo, const float4& hi, float d) {
    float4 st;
    __half2* hp = (__half2*)&st;
    hp[0] = __floats2half2_rn(lo.x * d, lo.y * d);
    hp[1] = __floats2half2_rn(lo.z * d, lo.w * d);
    hp[2] = __floats2half2_rn(hi.x * d, hi.y * d);
    hp[3] = __floats2half2_rn(hi.z * d, hi.w * d);
    *(float4*)p = st;
}

// ---------------- W1 & W2 -> B-fragment pre-pack + bucket_fill zero + zero rows ----------------
__global__ __launch_bounds__(256) void k_wprep(const float* __restrict__ W1,
                                               const float* __restrict__ W2,
                                               __half* __restrict__ w1frag,
                                               __half* __restrict__ w2frag,
                                               int* __restrict__ bucket_fill,
                                               __half* __restrict__ xw1h,
                                               __half* __restrict__ hw2p) {
    int t = threadIdx.x;
    if (blockIdx.x == 5 && t < NB) bucket_fill[t] = 0;
    if (blockIdx.x == 0 && t < 13) {     // zero row NN of both gather tables (dummy target)
        float4 z = make_float4(0.f, 0.f, 0.f, 0.f);
        if (t < 8) ((float4*)(xw1h + (size_t)NN * HID))[t] = z;
        else       ((float4*)(hw2p + (size_t)NN * 40))[t - 8] = z;
    }
    int e = blockIdx.x * 256 + t;
    if (e < 1024) {
        int ct = e >> 8, ki = (e >> 6) & 3, l = e & 63;
        int q = l >> 4, n = l & 15;
        v8h o;
        #pragma unroll
        for (int j = 0; j < 8; ++j)
            o[j] = (_Float16)W1[(ki * 32 + q * 8 + j) * 64 + ct * 16 + n];
        ((v8h*)w1frag)[e] = o;
    } else {
        int e2 = e - 1024;
        if (e2 < 384) {
            int ct = e2 >> 7, ki = (e2 >> 6) & 1, l = e2 & 63;
            int q = l >> 4, n = l & 15;
            int col = ct * 16 + n;
            v8h o;
            #pragma unroll
            for (int j = 0; j < 8; ++j)
                o[j] = (col < DOUT) ? (_Float16)W2[(ki * 32 + q * 8 + j) * DOUT + col]
                                    : (_Float16)0.0f;
            ((v8h*)w2frag)[e2] = o;
        }
    }
}

// ---------------- fat kernel: edge scatter (blocks < S_BLKS) || gemm1 (rest) ----------------
__global__ __launch_bounds__(256) void k_fat(const int* __restrict__ src,
                                             const int* __restrict__ dst,
                                             int* __restrict__ bucket_fill,
                                             int* __restrict__ ebuf,
                                             const float* __restrict__ x,
                                             const __half* __restrict__ w1frag,
                                             __half* __restrict__ xw1h) {
    __shared__ int smem[4096];           // 16 KB union
    int t = threadIdx.x;
    if (blockIdx.x < S_BLKS) {
        int* hist  = smem;
        int* gbase = smem + 256;
        int* rcur  = smem + 512;
        for (int i = t; i < NB; i += 256) { hist[i] = 0; rcur[i] = 0; }
        __syncthreads();
        int e0 = blockIdx.x * CH;
        int ep[16], eb[16];
        #pragma unroll
        for (int j = 0; j < 16; ++j) {
            int e = e0 + j * 256 + t;
            bool valid = (e < EE);
            if (valid) {
                int dd_ = dst[e];
                ep[j] = (src[e] << 9) | (dd_ & 511);
                eb[j] = dd_ >> 9;
                atomicAdd(&hist[eb[j]], 1);
            } else {
                ep[j] = 0; eb[j] = -1;
            }
        }
        __syncthreads();
        for (int i = t; i < NB; i += 256)
            gbase[i] = atomicAdd(&bucket_fill[i], hist[i]);
        __syncthreads();
        #pragma unroll
        for (int j = 0; j < 16; ++j) {
            if (eb[j] >= 0) {
                int r = atomicAdd(&rcur[eb[j]], 1);
                ebuf[eb[j] * SEG + gbase[eb[j]] + r] = ep[j];
            }
        }
    } else {
        float4* sb4 = (float4*)smem;     // 1024 float4 = 16 KB
        const float4* wf = (const float4*)w1frag;
        #pragma unroll
        for (int i = 0; i < 4; ++i) sb4[t + i * 256] = wf[t + i * 256];
        __syncthreads();
        const v8h* sbh = (const v8h*)sb4;
        int wv = t >> 6, l = t & 63;
        int q = l >> 4, n = l & 15;
        int row0 = (blockIdx.x - S_BLKS) * 64 + wv * 16;
        int m = row0 + n;
        bool mv = (m < NN);
        const float* xr = x + (size_t)(mv ? m : 0) * DIN + q * 8;
        v8h afrag[4];
        #pragma unroll
        for (int ki = 0; ki < 4; ++ki) {
            float4 u0 = mv ? ((const float4*)(xr + ki * 32))[0] : make_float4(0.f,0.f,0.f,0.f);
            float4 u1 = mv ? ((const float4*)(xr + ki * 32))[1] : make_float4(0.f,0.f,0.f,0.f);
            v8h a;
            a[0] = (_Float16)u0.x; a[1] = (_Float16)u0.y;
            a[2] = (_Float16)u0.z; a[3] = (_Float16)u0.w;
            a[4] = (_Float16)u1.x; a[5] = (_Float16)u1.y;
            a[6] = (_Float16)u1.z; a[7] = (_Float16)u1.w;
            afrag[ki] = a;
        }
        v4f acc[4];
        #pragma unroll
        for (int ct = 0; ct < 4; ++ct) acc[ct] = (v4f){0.f, 0.f, 0.f, 0.f};
        #pragma unroll
        for (int ct = 0; ct < 4; ++ct) {
            #pragma unroll
            for (int ki = 0; ki < 4; ++ki)
                acc[ct] = __builtin_amdgcn_mfma_f32_16x16x32_f16(
                    afrag[ki], sbh[(ct * 4 + ki) * 64 + l], acc[ct], 0, 0, 0);
        }
        _Float16* outh = (_Float16*)xw1h;
        #pragma unroll
        for (int r = 0; r < 4; ++r) {
            int rr = row0 + q * 4 + r;
            if (rr < NN) {
                #pragma unroll
                for (int ct = 0; ct < 4; ++ct)
                    outh[(size_t)rr * HID + ct * 16 + n] = (_Float16)acc[ct][r];
            }
        }
    }
}

// ---------------- per-bucket CSR (8-padded) + degree-sort perm + dinv + xw1h scaling ----------------
__global__ __launch_bounds__(512) void kB_csr(const int* __restrict__ ebuf,
                                              const int* __restrict__ bucket_fill,
                                              int* __restrict__ pofs,
                                              float* __restrict__ dinv,
                                              int* __restrict__ esrc,
                                              __half* __restrict__ xw1h,
                                              int* __restrict__ bperm) {
    __shared__ int lcnt[BN], sAa[BN], sBb[BN], lcur[BN];
    __shared__ int hbin[64];
    int t = threadIdx.x;
    int b = blockIdx.x;
    int eb0 = b * SEG;
    int eb2 = b * SEG2;
    int ecnt = bucket_fill[b];
    lcnt[t] = 0;
    if (t < 64) hbin[t] = 0;
    __syncthreads();
    for (int j = t; j < ecnt; j += 512)
        atomicAdd(&lcnt[ebuf[eb0 + j] & 511], 1);
    __syncthreads();
    int cnt  = lcnt[t];
    int pcnt = (cnt + 7) & ~7;           // pad each dst's list to a multiple of 8
    sAa[t] = pcnt;
    int base_node = b * BN;
    int node = base_node + t;
    bool real = (node < NN);
    // ---- bucket-local counting sort by degree -> bperm (slot -> node) ----
    // makes the 8 groups of every gather wave have near-equal list lengths
    int key = min(cnt, 63);
    if (real) atomicAdd(&hbin[key], 1);
    __syncthreads();
    if (t == 0) {
        int run = 0;
        for (int i = 0; i < 64; ++i) { int c = hbin[i]; hbin[i] = run; run += c; }
    }
    __syncthreads();
    if (real) {
        int r = atomicAdd(&hbin[key], 1);
        bperm[base_node + r] = node;
    }
    // ---- exclusive scan of padded counts ----
    int* s = sAa; int* d = sBb;
    for (int off = 1; off < BN; off <<= 1) {
        d[t] = s[t] + ((t >= off) ? s[t - off] : 0);
        __syncthreads();
        int* tmp = s; s = d; d = tmp;
    }
    int excl = s[t] - pcnt;
    lcur[t] = excl;
    if (real) {
        pofs[node] = ((eb2 + excl) << 10) | pcnt;     // padded base + padded count
        dinv[node] = rsqrtf((float)cnt + 1.0f);       // +1 self-loop (real count)
    }
    // slack-only dummy fill (<=7 slots per node; pad slots gather zero row NN)
    for (int i = excl + cnt; i < excl + pcnt; ++i) esrc[eb2 + i] = NN;
    __syncthreads();
    for (int j = t; j < ecnt; j += 512) {
        int p = ebuf[eb0 + j];
        int r = atomicAdd(&lcur[p & 511], 1);
        esrc[eb2 + r] = p >> 9;          // plain src id
    }
    // scale this bucket's xw1h rows by dinv (k_fat wrote them unscaled)
    float4* xr4 = (float4*)xw1h;
    for (int i = t; i < BN * 8; i += 512) {
        int li = i >> 3;
        int node2 = base_node + li;
        if (node2 < NN) {
            float di = rsqrtf((float)lcnt[li] + 1.0f);
            float4 v = xr4[(size_t)node2 * 8 + (i & 7)];
            __half2* h = (__half2*)&v;
            #pragma unroll
            for (int u = 0; u < 4; ++u) {
                float2 f = __half22float2(h[u]);
                h[u] = __floats2half2_rn(f.x * di, f.y * di);
            }
            xr4[(size_t)node2 * 8 + (i & 7)] = v;
        }
    }
}

// ---------------- fused: layer-1 aggregation (degree-sorted dsts, max occupancy) + layer-2 GEMM ----------------
// Phase A: 32 groups x 8 lanes; group g owns dst bperm[d0+g]. Degree-sorted
// slots give each wave's 8 groups near-equal list lengths -> max over groups
// ~= mean (removes ~1.5x lockstep-idle waste). Padded-to-8 lists keep every
// iteration a full branch-free 8-deep burst; 8 waves/SIMD hide gather latency.
// Phase B: 2 waves x 16 slot-rows; MFMA is row-independent, outputs scatter to
// bperm[slot] as PACKED 40-half pre-scaled hw2p rows.
__global__ __launch_bounds__(256, 8) void k_fuse(const __half* __restrict__ xw1h,
                                                 const float* __restrict__ dinv,
                                                 const int* __restrict__ pofs,
                                                 const int* __restrict__ esrc,
                                                 const float* __restrict__ b1,
                                                 const __half* __restrict__ w2frag,
                                                 __half* __restrict__ hw2p,
                                                 const int* __restrict__ bperm) {
    __shared__ __half sh[32 * 72];       // 4.5 KB agg rows (slot-ordered, stride 144 B)
    __shared__ float4 sb4[384];          // 6 KB: W2 B-frags
    __shared__ float sb1[64];
    int t = threadIdx.x;
    const float4* wf = (const float4*)w2frag;
    if (t < 192) { sb4[t] = wf[t]; sb4[t + 192] = wf[t + 192]; }
    if (t >= 192) sb1[t - 192] = b1[t - 192];

    int d0 = blockIdx.x * 32;
    int g = t >> 3, q = t & 7;
    int dd = bperm[d0 + g];              // degree-sorted slot -> actual dst
    const float4* tab4 = (const float4*)xw1h;
    float4 tl = make_float4(0.f,0.f,0.f,0.f), th = make_float4(0.f,0.f,0.f,0.f);
    acc8(tab4[(size_t)dd * 8 + q], tl, th);        // self-loop (row pre-scaled)
    int p_ = pofs[dd];
    int j = p_ >> 10;
    int n8 = (p_ & 1023) >> 3;
    for (int m = 0; m < n8; ++m, j += 8) {
        int e[8];
        float4 v[8];
        #pragma unroll
        for (int u = 0; u < 8; ++u) e[u] = esrc[j + u];
        #pragma unroll
        for (int u = 0; u < 8; ++u) v[u] = tab4[(size_t)e[u] * 8 + q];
        #pragma unroll
        for (int u = 0; u < 8; ++u) acc8(v[u], tl, th);
    }
    sthalf8(sh + g * 72 + q * 8, tl, th, dinv[dd]);
    __syncthreads();

    // phase B: waves 0-1, 16 slot-rows each, 6 MFMAs
    int wv = t >> 6, l = t & 63;
    if (wv < 2) {
        const v8h* sbh = (const v8h*)sb4;
        int qq = l >> 4, n = l & 15;
        int srow = wv * 16 + n;
        v8h afrag[2];
        #pragma unroll
        for (int ki = 0; ki < 2; ++ki) {
            v8h a = *(const v8h*)(sh + srow * 72 + ki * 32 + qq * 8);
            #pragma unroll
            for (int jj = 0; jj < 8; ++jj) {
                float av = (float)a[jj] + sb1[ki * 32 + qq * 8 + jj];
                a[jj] = (_Float16)fmaxf(av, 0.f);
            }
            afrag[ki] = a;
        }
        v4f acc[3];
        #pragma unroll
        for (int ct = 0; ct < 3; ++ct) acc[ct] = (v4f){0.f, 0.f, 0.f, 0.f};
        #pragma unroll
        for (int ct = 0; ct < 3; ++ct) {
            #pragma unroll
            for (int ki = 0; ki < 2; ++ki)
                acc[ct] = __builtin_amdgcn_mfma_f32_16x16x32_f16(
                    afrag[ki], sbh[(ct * 2 + ki) * 64 + l], acc[ct], 0, 0, 0);
        }
        // scatter packed 40-half rows to actual dst rows, pre-scaled by dinv
        _Float16* outh = (_Float16*)hw2p;
        #pragma unroll
        for (int r = 0; r < 4; ++r) {
            int slot = d0 + wv * 16 + qq * 4 + r;
            int rr = bperm[slot];
            float di = dinv[rr];
            outh[(size_t)rr * 40 + n]      = (_Float16)(acc[0][r] * di);
            outh[(size_t)rr * 40 + 16 + n] = (_Float16)(acc[1][r] * di);
            if (n < 8)
                outh[(size_t)rr * 40 + 32 + n] = (_Float16)(acc[2][r] * di);
        }
    }
}

// ---------------- layer 2 aggregation: degree-sorted dsts, packed 80B rows, no LDS ----------------
__global__ __launch_bounds__(256, 8) void k_agg2(const __half* __restrict__ hw2p,
                                                 const float* __restrict__ dinv,
                                                 const int* __restrict__ pofs,
                                                 const int* __restrict__ esrc,
                                                 const float* __restrict__ b2,
                                                 float* __restrict__ out,
                                                 const int* __restrict__ bperm) {
    int t = threadIdx.x;
    int g = t >> 3, q = t & 7;
    int qc = (q < 5) ? q : (q - 3);      // lanes 5-7 duplicate granules 2-4 (coalescer merges)
    int dd = bperm[blockIdx.x * 32 + g]; // degree-sorted slot -> actual dst
    const float4* tab4 = (const float4*)hw2p;
    float4 tl = make_float4(0.f,0.f,0.f,0.f), th = make_float4(0.f,0.f,0.f,0.f);
    acc8(tab4[(size_t)dd * 5 + qc], tl, th);       // self-loop (pre-scaled)
    int p_ = pofs[dd];
    int j = p_ >> 10;
    int n8 = (p_ & 1023) >> 3;
    for (int m = 0; m < n8; ++m, j += 8) {
        int e[8];
        float4 v[8];
        #pragma unroll
        for (int u = 0; u < 8; ++u) e[u] = esrc[j + u];
        #pragma unroll
        for (int u = 0; u < 8; ++u) v[u] = tab4[(size_t)e[u] * 5 + qc];
        #pragma unroll
        for (int u = 0; u < 8; ++u) acc8(v[u], tl, th);
    }
    if (q < 5) {                         // channels q*8 .. q*8+7 (40 total)
        float di = dinv[dd];
        const float4* b24 = (const float4*)(b2 + q * 8);
        float4 c0 = b24[0], c1 = b24[1];
        float* op = out + (size_t)dd * DOUT + q * 8;
        ((float4*)op)[0] = make_float4(tl.x * di + c0.x, tl.y * di + c0.y,
                                       tl.z * di + c0.z, tl.w * di + c0.w);
        ((float4*)op)[1] = make_float4(th.x * di + c1.x, th.y * di + c1.y,
                                       th.z * di + c1.z, th.w * di + c1.w);
    }
}

extern "C" void kernel_launch(void* const* d_in, const int* in_sizes, int n_in,
                              void* d_out, int out_size, void* d_ws, size_t ws_size,
                              hipStream_t stream) {
    const float* x  = (const float*)d_in[0];
    const float* W1 = (const float*)d_in[1];
    const float* b1 = (const float*)d_in[2];
    const float* W2 = (const float*)d_in[3];
    const float* b2 = (const float*)d_in[4];
    const int*   ei = (const int*)d_in[5];
    const int* src = ei;        // edge_index[0]
    const int* dst = ei + EE;   // edge_index[1]
    float* out = (float*)d_out;

    float* ws = (float*)d_ws;
    int*    bucket_fill = (int*)ws;                     // [0,256)
    int*    pofs        = (int*)ws + 256;               // NN
    float*  dinv        = ws + 100352;                  // NN
    int*    ebuf        = (int*)ws + 200704;            // NB*SEG  = 1,605,632
    int*    esrc        = (int*)ws + 1806336;           // NB*SEG2 = 2,007,040
    __half* xw1h        = (__half*)(ws + 3813376);      // (NN+1)*64 halves (pre-scaled; row NN = 0)
    __half* hw2p        = (__half*)(ws + 7013408);      // (NN+1)*40 halves (packed, pre-scaled; row NN = 0)
    __half* w1frag      = (__half*)(ws + 9013428);      // 8192 halves
    __half* w2frag      = (__half*)(ws + 9017524);      // 3072 halves
    int*    bperm       = (int*)ws + 9019060;           // NN (slot -> node, degree-sorted per bucket)
    // total: 9,119,060 floats = 36.5 MB

    k_wprep <<<6, 256, 0, stream>>>(W1, W2, w1frag, w2frag, bucket_fill, xw1h, hw2p);
    k_fat   <<<S_BLKS + G_BLKS, 256, 0, stream>>>(src, dst, bucket_fill, ebuf, x, w1frag, xw1h);
    kB_csr  <<<NB, 512, 0, stream>>>(ebuf, bucket_fill, pofs, dinv, esrc, xw1h, bperm);
    k_fuse  <<<NN / 32, 256, 0, stream>>>(xw1h, dinv, pofs, esrc, b1, w2frag, hw2p, bperm);
    k_agg2  <<<NN / 32, 256, 0, stream>>>(hw2p, dinv, pofs, esrc, b2, out, bperm);
}

// Round 9
// 179.934 us; speedup vs baseline: 1.1178x; 1.1178x over previous
//
#include <hip/hip_runtime.h>
#include <hip/hip_fp16.h>

#define NN   100000
#define EE   1250000
#define DIN  128
#define HID  64
#define DOUT 40

#define BN   512                  // nodes per bucket
#define NB   196                  // ceil(NN/BN)
#define CH   4096                 // edges per scatter block (16/thread)
#define SEG  8192                 // ebuf stride (raw edges; mean 6377, 22 sigma)
#define SEG2 10240                // esrc stride (8-padded lists; mean ~8170, big margin)
#define S_BLKS 306                // ceil(EE/CH)
#define G_BLKS 1563               // ceil(NN/64)

typedef _Float16 v8h __attribute__((ext_vector_type(8)));
typedef float    v4f __attribute__((ext_vector_type(4)));

// unpack a float4-of-8-halves and accumulate into 2 float4s
__device__ __forceinline__ void acc8(const float4& v, float4& lo, float4& hi) {
    const __half2* hp = (const __half2*)&v;
    float2 f0 = __half22float2(hp[0]), f1 = __half22float2(hp[1]);
    float2 f2 = __half22float2(hp[2]), f3 = __half22float2(hp[3]);
    lo.x += f0.x; lo.y += f0.y; lo.z += f1.x; lo.w += f1.y;
    hi.x += f2.x; hi.y += f2.y; hi.z += f3.x; hi.w += f3.y;
}

// scale by d, convert to 8 halves, store 16B
__device__ __forceinline__ void sthalf8(__half* p, const float4& lo, const float4& hi, float d) {
    float4 st;
    __half2* hp = (__half2*)&st;
    hp[0] = __floats2half2_rn(lo.x * d, lo.y * d);
    hp[1] = __floats2half2_rn(lo.z * d, lo.w * d);
    hp[2] = __floats2half2_rn(hi.x * d, hi.y * d);
    hp[3] = __floats2half2_rn(hi.z * d, hi.w * d);
    *(float4*)p = st;
}

// ---------------- W1 & W2 -> B-fragment pre-pack + bucket_fill zero + zero rows ----------------
__global__ __launch_bounds__(256) void k_wprep(const float* __restrict__ W1,
                                               const float* __restrict__ W2,
                                               __half* __restrict__ w1frag,
                                               __half* __restrict__ w2frag,
                                               int* __restrict__ bucket_fill,
                                               __half* __restrict__ xw1h,
                                               __half* __restrict__ hw2p) {
    int t = threadIdx.x;
    if (blockIdx.x == 5 && t < NB) bucket_fill[t] = 0;
    if (blockIdx.x == 0 && t < 16) {     // zero row NN of both gather tables (dummy target)
        float4 z = make_float4(0.f, 0.f, 0.f, 0.f);
        if (t < 8) ((float4*)(xw1h + (size_t)NN * HID))[t] = z;
        else       ((float4*)(hw2p + (size_t)NN * HID))[t - 8] = z;
    }
    int e = blockIdx.x * 256 + t;
    if (e < 1024) {
        int ct = e >> 8, ki = (e >> 6) & 3, l = e & 63;
        int q = l >> 4, n = l & 15;
        v8h o;
        #pragma unroll
        for (int j = 0; j < 8; ++j)
            o[j] = (_Float16)W1[(ki * 32 + q * 8 + j) * 64 + ct * 16 + n];
        ((v8h*)w1frag)[e] = o;
    } else {
        int e2 = e - 1024;
        if (e2 < 384) {
            int ct = e2 >> 7, ki = (e2 >> 6) & 1, l = e2 & 63;
            int q = l >> 4, n = l & 15;
            int col = ct * 16 + n;
            v8h o;
            #pragma unroll
            for (int j = 0; j < 8; ++j)
                o[j] = (col < DOUT) ? (_Float16)W2[(ki * 32 + q * 8 + j) * DOUT + col]
                                    : (_Float16)0.0f;
            ((v8h*)w2frag)[e2] = o;
        }
    }
}

// ---------------- fat kernel: edge scatter (blocks < S_BLKS) || gemm1 (rest) ----------------
__global__ __launch_bounds__(256) void k_fat(const int* __restrict__ src,
                                             const int* __restrict__ dst,
                                             int* __restrict__ bucket_fill,
                                             int* __restrict__ ebuf,
                                             const float* __restrict__ x,
                                             const __half* __restrict__ w1frag,
                                             __half* __restrict__ xw1h) {
    __shared__ int smem[4096];           // 16 KB union
    int t = threadIdx.x;
    if (blockIdx.x < S_BLKS) {
        int* hist  = smem;
        int* gbase = smem + 256;
        int* rcur  = smem + 512;
        for (int i = t; i < NB; i += 256) { hist[i] = 0; rcur[i] = 0; }
        __syncthreads();
        int e0 = blockIdx.x * CH;
        int ep[16], eb[16];
        #pragma unroll
        for (int j = 0; j < 16; ++j) {
            int e = e0 + j * 256 + t;
            bool valid = (e < EE);
            if (valid) {
                int dd_ = dst[e];
                ep[j] = (src[e] << 9) | (dd_ & 511);
                eb[j] = dd_ >> 9;
                atomicAdd(&hist[eb[j]], 1);
            } else {
                ep[j] = 0; eb[j] = -1;
            }
        }
        __syncthreads();
        for (int i = t; i < NB; i += 256)
            gbase[i] = atomicAdd(&bucket_fill[i], hist[i]);
        __syncthreads();
        #pragma unroll
        for (int j = 0; j < 16; ++j) {
            if (eb[j] >= 0) {
                int r = atomicAdd(&rcur[eb[j]], 1);
                ebuf[eb[j] * SEG + gbase[eb[j]] + r] = ep[j];
            }
        }
    } else {
        float4* sb4 = (float4*)smem;     // 1024 float4 = 16 KB
        const float4* wf = (const float4*)w1frag;
        #pragma unroll
        for (int i = 0; i < 4; ++i) sb4[t + i * 256] = wf[t + i * 256];
        __syncthreads();
        const v8h* sbh = (const v8h*)sb4;
        int wv = t >> 6, l = t & 63;
        int q = l >> 4, n = l & 15;
        int row0 = (blockIdx.x - S_BLKS) * 64 + wv * 16;
        int m = row0 + n;
        bool mv = (m < NN);
        const float* xr = x + (size_t)(mv ? m : 0) * DIN + q * 8;
        v8h afrag[4];
        #pragma unroll
        for (int ki = 0; ki < 4; ++ki) {
            float4 u0 = mv ? ((const float4*)(xr + ki * 32))[0] : make_float4(0.f,0.f,0.f,0.f);
            float4 u1 = mv ? ((const float4*)(xr + ki * 32))[1] : make_float4(0.f,0.f,0.f,0.f);
            v8h a;
            a[0] = (_Float16)u0.x; a[1] = (_Float16)u0.y;
            a[2] = (_Float16)u0.z; a[3] = (_Float16)u0.w;
            a[4] = (_Float16)u1.x; a[5] = (_Float16)u1.y;
            a[6] = (_Float16)u1.z; a[7] = (_Float16)u1.w;
            afrag[ki] = a;
        }
        v4f acc[4];
        #pragma unroll
        for (int ct = 0; ct < 4; ++ct) acc[ct] = (v4f){0.f, 0.f, 0.f, 0.f};
        #pragma unroll
        for (int ct = 0; ct < 4; ++ct) {
            #pragma unroll
            for (int ki = 0; ki < 4; ++ki)
                acc[ct] = __builtin_amdgcn_mfma_f32_16x16x32_f16(
                    afrag[ki], sbh[(ct * 4 + ki) * 64 + l], acc[ct], 0, 0, 0);
        }
        _Float16* outh = (_Float16*)xw1h;
        #pragma unroll
        for (int r = 0; r < 4; ++r) {
            int rr = row0 + q * 4 + r;
            if (rr < NN) {
                #pragma unroll
                for (int ct = 0; ct < 4; ++ct)
                    outh[(size_t)rr * HID + ct * 16 + n] = (_Float16)acc[ct][r];
            }
        }
    }
}

// ---------------- per-bucket CSR (8-padded) + dinv + xw1h scaling (512 threads) ----------------
__global__ __launch_bounds__(512) void kB_csr(const int* __restrict__ ebuf,
                                              const int* __restrict__ bucket_fill,
                                              int* __restrict__ pofs,
                                              float* __restrict__ dinv,
                                              int* __restrict__ esrc,
                                              __half* __restrict__ xw1h) {
    __shared__ int lcnt[BN], sAa[BN], sBb[BN], lcur[BN];
    int t = threadIdx.x;
    int b = blockIdx.x;
    int eb0 = b * SEG;
    int eb2 = b * SEG2;
    int ecnt = bucket_fill[b];
    lcnt[t] = 0;
    __syncthreads();
    for (int j = t; j < ecnt; j += 512)
        atomicAdd(&lcnt[ebuf[eb0 + j] & 511], 1);
    __syncthreads();
    int cnt  = lcnt[t];
    int pcnt = (cnt + 7) & ~7;           // pad each dst's list to a multiple of 8
    sAa[t] = pcnt;
    __syncthreads();
    int* s = sAa; int* d = sBb;
    for (int off = 1; off < BN; off <<= 1) {
        d[t] = s[t] + ((t >= off) ? s[t - off] : 0);
        __syncthreads();
        int* tmp = s; s = d; d = tmp;
    }
    int base_node = b * BN;
    int excl = s[t] - pcnt;              // padded exclusive offset
    lcur[t] = excl;
    int node = base_node + t;
    if (node < NN) {
        pofs[node] = ((eb2 + excl) << 10) | pcnt;     // padded base + padded count
        dinv[node] = rsqrtf((float)cnt + 1.0f);       // +1 self-loop (real count)
    }
    // slack-only dummy fill (<=7 slots per node; pad slots gather zero row NN)
    for (int i = excl + cnt; i < excl + pcnt; ++i) esrc[eb2 + i] = NN;
    __syncthreads();
    for (int j = t; j < ecnt; j += 512) {
        int p = ebuf[eb0 + j];
        int r = atomicAdd(&lcur[p & 511], 1);
        esrc[eb2 + r] = p >> 9;          // plain src id
    }
    // scale this bucket's xw1h rows by dinv (k_fat wrote them unscaled)
    float4* xr4 = (float4*)xw1h;
    for (int i = t; i < BN * 8; i += 512) {
        int li = i >> 3;
        int node2 = base_node + li;
        if (node2 < NN) {
            float di = rsqrtf((float)lcnt[li] + 1.0f);
            float4 v = xr4[(size_t)node2 * 8 + (i & 7)];
            __half2* h = (__half2*)&v;
            #pragma unroll
            for (int u = 0; u < 4; ++u) {
                float2 f = __half22float2(h[u]);
                h[u] = __floats2half2_rn(f.x * di, f.y * di);
            }
            xr4[(size_t)node2 * 8 + (i & 7)] = v;
        }
    }
}

// ---------------- fused: layer-1 aggregation (1 dst/group, max occupancy) + layer-2 GEMM ----------------
// Phase A: 32 groups x 8 lanes; group g owns dst d0+g. Padded-to-8 lists make
// every iteration a full branch-free 8-deep gather burst (no remainder tail).
// Lean register footprint (<=64 VGPR) -> 8 waves/SIMD: TLP hides gather latency.
// Phase B: 2 waves x 16 rows; A-frags from LDS halves (+bias+relu), 6 MFMAs;
// epilogue writes 128B-ALIGNED 64-half rows of hw2p (cols 40-47 true zeros,
// 48-63 dead), pre-scaled by dinv[row] -> every layer-2 gather is ONE L2 line.
__global__ __launch_bounds__(256, 8) void k_fuse(const __half* __restrict__ xw1h,
                                                 const float* __restrict__ dinv,
                                                 const int* __restrict__ pofs,
                                                 const int* __restrict__ esrc,
                                                 const float* __restrict__ b1,
                                                 const __half* __restrict__ w2frag,
                                                 __half* __restrict__ hw2p) {
    __shared__ __half sh[32 * 72];       // 4.5 KB agg rows (stride 144 B, 16B-aligned)
    __shared__ float4 sb4[384];          // 6 KB: W2 B-frags
    __shared__ float sb1[64];
    int t = threadIdx.x;
    const float4* wf = (const float4*)w2frag;
    if (t < 192) { sb4[t] = wf[t]; sb4[t + 192] = wf[t + 192]; }
    if (t >= 192) sb1[t - 192] = b1[t - 192];

    int d0 = blockIdx.x * 32;
    int g = t >> 3, q = t & 7;
    int dd = d0 + g;                     // grid = NN/32 exactly: always < NN
    const float4* tab4 = (const float4*)xw1h;
    float4 tl = make_float4(0.f,0.f,0.f,0.f), th = make_float4(0.f,0.f,0.f,0.f);
    acc8(tab4[(size_t)dd * 8 + q], tl, th);        // self-loop (row pre-scaled)
    int p_ = pofs[dd];
    int j = p_ >> 10;
    int n8 = (p_ & 1023) >> 3;
    for (int m = 0; m < n8; ++m, j += 8) {
        int e[8];
        float4 v[8];
        #pragma unroll
        for (int u = 0; u < 8; ++u) e[u] = esrc[j + u];
        #pragma unroll
        for (int u = 0; u < 8; ++u) v[u] = tab4[(size_t)e[u] * 8 + q];
        #pragma unroll
        for (int u = 0; u < 8; ++u) acc8(v[u], tl, th);
    }
    sthalf8(sh + g * 72 + q * 8, tl, th, dinv[dd]);
    __syncthreads();

    // phase B: waves 0-1, 16 rows each, 6 MFMAs
    int wv = t >> 6, l = t & 63;
    if (wv < 2) {
        const v8h* sbh = (const v8h*)sb4;
        int qq = l >> 4, n = l & 15;
        int srow = wv * 16 + n;
        v8h afrag[2];
        #pragma unroll
        for (int ki = 0; ki < 2; ++ki) {
            v8h a = *(const v8h*)(sh + srow * 72 + ki * 32 + qq * 8);
            #pragma unroll
            for (int jj = 0; jj < 8; ++jj) {
                float av = (float)a[jj] + sb1[ki * 32 + qq * 8 + jj];
                a[jj] = (_Float16)fmaxf(av, 0.f);
            }
            afrag[ki] = a;
        }
        v4f acc[3];
        #pragma unroll
        for (int ct = 0; ct < 3; ++ct) acc[ct] = (v4f){0.f, 0.f, 0.f, 0.f};
        #pragma unroll
        for (int ct = 0; ct < 3; ++ct) {
            #pragma unroll
            for (int ki = 0; ki < 2; ++ki)
                acc[ct] = __builtin_amdgcn_mfma_f32_16x16x32_f16(
                    afrag[ki], sbh[(ct * 2 + ki) * 64 + l], acc[ct], 0, 0, 0);
        }
        // 128B-aligned 64-half rows, pre-scaled by dinv[row] (cols 40-47 = 0)
        _Float16* outh = (_Float16*)hw2p;
        #pragma unroll
        for (int r = 0; r < 4; ++r) {
            int rr = d0 + wv * 16 + qq * 4 + r;
            float di = dinv[rr];
            #pragma unroll
            for (int ct = 0; ct < 3; ++ct)
                outh[(size_t)rr * HID + ct * 16 + n] = (_Float16)(acc[ct][r] * di);
        }
    }
}

// ---------------- layer 2 aggregation: 1 dst/group, 128B rows, no LDS, max occupancy ----------------
__global__ __launch_bounds__(256, 8) void k_agg2(const __half* __restrict__ hw2p,
                                                 const float* __restrict__ dinv,
                                                 const int* __restrict__ pofs,
                                                 const int* __restrict__ esrc,
                                                 const float* __restrict__ b2,
                                                 float* __restrict__ out) {
    int t = threadIdx.x;
    int g = t >> 3, q = t & 7;           // lanes 6-7 accumulate dead cols (discarded)
    int dd = blockIdx.x * 32 + g;        // grid = NN/32 exactly
    const float4* tab4 = (const float4*)hw2p;
    float4 tl = make_float4(0.f,0.f,0.f,0.f), th = make_float4(0.f,0.f,0.f,0.f);
    acc8(tab4[(size_t)dd * 8 + q], tl, th);        // self-loop (pre-scaled)
    int p_ = pofs[dd];
    int j = p_ >> 10;
    int n8 = (p_ & 1023) >> 3;
    for (int m = 0; m < n8; ++m, j += 8) {
        int e[8];
        float4 v[8];
        #pragma unroll
        for (int u = 0; u < 8; ++u) e[u] = esrc[j + u];
        #pragma unroll
        for (int u = 0; u < 8; ++u) v[u] = tab4[(size_t)e[u] * 8 + q];
        #pragma unroll
        for (int u = 0; u < 8; ++u) acc8(v[u], tl, th);
    }
    if (q < 5) {                         // channels q*8 .. q*8+7 (40 total)
        float di = dinv[dd];
        const float4* b24 = (const float4*)(b2 + q * 8);
        float4 c0 = b24[0], c1 = b24[1];
        float* op = out + (size_t)dd * DOUT + q * 8;
        ((float4*)op)[0] = make_float4(tl.x * di + c0.x, tl.y * di + c0.y,
                                       tl.z * di + c0.z, tl.w * di + c0.w);
        ((float4*)op)[1] = make_float4(th.x * di + c1.x, th.y * di + c1.y,
                                       th.z * di + c1.z, th.w * di + c1.w);
    }
}

extern "C" void kernel_launch(void* const* d_in, const int* in_sizes, int n_in,
                              void* d_out, int out_size, void* d_ws, size_t ws_size,
                              hipStream_t stream) {
    const float* x  = (const float*)d_in[0];
    const float* W1 = (const float*)d_in[1];
    const float* b1 = (const float*)d_in[2];
    const float* W2 = (const float*)d_in[3];
    const float* b2 = (const float*)d_in[4];
    const int*   ei = (const int*)d_in[5];
    const int* src = ei;        // edge_index[0]
    const int* dst = ei + EE;   // edge_index[1]
    float* out = (float*)d_out;

    float* ws = (float*)d_ws;
    int*    bucket_fill = (int*)ws;                     // [0,256)
    int*    pofs        = (int*)ws + 256;               // NN
    float*  dinv        = ws + 100352;                  // NN
    int*    ebuf        = (int*)ws + 200704;            // NB*SEG  = 1,605,632
    int*    esrc        = (int*)ws + 1806336;           // NB*SEG2 = 2,007,040
    __half* xw1h        = (__half*)(ws + 3813376);      // (NN+1)*64 halves (pre-scaled; row NN = 0)
    __half* hw2p        = (__half*)(ws + 7013440);      // (NN+1)*64 halves (128B rows, pre-scaled; row NN = 0)
    __half* w1frag      = (__half*)(ws + 10213504);     // 8192 halves
    __half* w2frag      = (__half*)(ws + 10217600);     // 3072 halves
    // total: 10,219,136 floats = 40.9 MB

    k_wprep <<<6, 256, 0, stream>>>(W1, W2, w1frag, w2frag, bucket_fill, xw1h, hw2p);
    k_fat   <<<S_BLKS + G_BLKS, 256, 0, stream>>>(src, dst, bucket_fill, ebuf, x, w1frag, xw1h);
    kB_csr  <<<NB, 512, 0, stream>>>(ebuf, bucket_fill, pofs, dinv, esrc, xw1h);
    k_fuse  <<<NN / 32, 256, 0, stream>>>(xw1h, dinv, pofs, esrc, b1, w2frag, hw2p);
    k_agg2  <<<NN / 32, 256, 0, stream>>>(hw2p, dinv, pofs, esrc, b2, out);
}